// Round 7
// baseline (57.868 us; speedup 1.0000x reference)
//
#include <hip/hip_runtime.h>
#include <hip/hip_bf16.h>

typedef float    f32x4  __attribute__((ext_vector_type(4)));
typedef float    f32x16 __attribute__((ext_vector_type(16)));
typedef int      i32x4  __attribute__((ext_vector_type(4)));
typedef _Float16 f16x8  __attribute__((ext_vector_type(8)));

#define LL 256   // h*w
#define NF 32    // hidden dim
#define NCH 64   // channels
#define SCALE 65536.0f
#define INV_SCALE (1.0f/65536.0f)

// HW pack: two f32 -> u32 of two fp16 (v_cvt_pkrtz_f16_f32)
__device__ __forceinline__ unsigned pkrtz(float lo, float hi) {
    return __builtin_bit_cast(unsigned, __builtin_amdgcn_cvt_pkrtz(lo, hi));
}

__device__ __forceinline__ f16x8 words_to_frag(unsigned w0, unsigned w1, unsigned w2, unsigned w3) {
    i32x4 w;
    w.x = (int)w0; w.y = (int)w1; w.z = (int)w2; w.w = (int)w3;
    return __builtin_bit_cast(f16x8, w);
}

// ---------------- phase 0: A'[b,l,k] = o @ W0[:64] + b0 (fp16) ; B[b,l,k] = o @ W0[64:] (fp16) ----
// block 0 additionally re-zeroes the int64 accumulators + counter (graph-replay safe).
__global__ __launch_bounds__(256) void rn_pre(
    const float* __restrict__ x, const float* __restrict__ W0,
    const float* __restrict__ b0, _Float16* __restrict__ Ap, _Float16* __restrict__ Bp,
    unsigned long long* __restrict__ acc)
{
    if (blockIdx.x == 0) {
        #pragma unroll
        for (int i = threadIdx.x; i < 1032; i += 256) acc[i] = 0ULL;  // 1024 acc + counter pad
    }
    int gid = blockIdx.x * 256 + threadIdx.x;   // 32*256*32 = 262144 threads
    int k  = gid & 31;
    int bl = gid >> 5;          // b*256 + l
    int b  = bl >> 8;
    int l  = bl & 255;
    const float* xrow = x + b * NCH * LL + l;   // x[b][ch][l]
    float accA = 0.f, accB = 0.f;
    #pragma unroll 8
    for (int ch = 0; ch < NCH; ++ch) {
        float xv = xrow[ch * LL];
        accA += xv * W0[ch * NF + k];
        accB += xv * W0[(NCH + ch) * NF + k];
    }
    Ap[gid] = (_Float16)(accA + b0[k]);
    Bp[gid] = (_Float16)accB;
}

// ---------------- phase 1: fused pair loop + fixed-point global reduce + inline head ----------------
// grid: 2048 blocks (XCD-swizzled) = 32 batches x 16 pgroups x 4 qchunks; 256 threads (4 waves).
// Wave owns 4 consecutive p's x 2 q-tiles; 4 independent p-chains share the A'-tile load and one sacc.
// phi (hidden-dim 4-blocks 1<->2, 5<->6) folded into the W2 A-fragment (r3-verified).
// Block partials -> scaled-int64 atomicAdd (order-independent => deterministic); last block does head.
__global__ __launch_bounds__(256) void rn_main(
    const _Float16* __restrict__ Ap, const _Float16* __restrict__ Bp,
    const float* __restrict__ W1, const float* __restrict__ b1,
    const float* __restrict__ W2, const float* __restrict__ b2,
    unsigned long long* __restrict__ acc, unsigned int* __restrict__ counter,
    const float* __restrict__ Wp, const float* __restrict__ bp,
    const float* __restrict__ Wo, const float* __restrict__ bo,
    float* __restrict__ out)
{
    const int tid  = threadIdx.x;
    const int lane = tid & 63;
    const int w    = tid >> 6;
    const int col  = lane & 31;     // MFMA column index
    const int hi   = lane >> 5;     // half-wave
    // bijective XCD-contiguous swizzle (2048 % 8 == 0)
    const int bid  = (blockIdx.x & 7) * 256 + (blockIdx.x >> 3);
    const int batch  = bid >> 6;
    const int rem    = bid & 63;
    const int pgroup = rem >> 2;    // 0..15
    const int qchunk = rem & 3;     // 0..3
    const int pbase  = pgroup * 16 + w * 4;
    const int q0base = qchunk * 64;

    // ---- constant A-operand fragments ----
    f16x8 a1[2], a2[2];
    #pragma unroll
    for (int kh = 0; kh < 2; ++kh) {
        #pragma unroll
        for (int e = 0; e < 8; ++e) {
            int k  = kh * 16 + 8 * hi + e;
            int bk = (k >> 2) & 3;
            int fk = (bk == 1 || bk == 2) ? (k ^ 12) : k;   // phi
            a1[kh][e] = (_Float16)W1[k  * NF + col];
            a2[kh][e] = (_Float16)W2[fk * NF + col];
        }
    }

    // ---- biases in the C/D register layout: row = (r&3)+8*(r>>2)+4*hi ----
    f32x16 bias1, bias2, sacc;
    #pragma unroll
    for (int r = 0; r < 16; ++r) {
        int row = (r & 3) + 8 * (r >> 2) + 4 * hi;
        bias1[r] = b1[row];
        bias2[r] = b2[row];
        sacc[r]  = 0.f;
    }

    // ---- B rows for the wave's 4 p's (fragment order) ----
    f16x8 bq0[4], bq1[4];
    #pragma unroll
    for (int i = 0; i < 4; ++i) {
        const _Float16* Brow = Bp + (batch * LL + pbase + i) * NF + 8 * hi;
        bq0[i] = *(const f16x8*)(Brow);
        bq1[i] = *(const f16x8*)(Brow + 16);
    }

    const _Float16* Abase = Ap + batch * LL * NF + 8 * hi;
    const f16x8 z8 = {};

    #pragma unroll
    for (int t = 0; t < 2; ++t) {
        const _Float16* Arow = Abase + (q0base + t * 32 + col) * NF;
        f16x8 t0 = *(const f16x8*)(Arow);
        f16x8 t1 = *(const f16x8*)(Arow + 16);

        #pragma unroll
        for (int i = 0; i < 4; ++i) {
            // h1 = relu(A'[q] + B[p_i]) in fp16 (v_pk_add_f16 + v_pk_max_f16)
            f16x8 h0 = __builtin_elementwise_max(t0 + bq0[i], z8);
            f16x8 h1 = __builtin_elementwise_max(t1 + bq1[i], z8);

            // layer 1 (bias as C-input)
            f32x16 acc1 = __builtin_amdgcn_mfma_f32_32x32x16_f16(a1[0], h0, bias1, 0, 0, 0);
            acc1        = __builtin_amdgcn_mfma_f32_32x32x16_f16(a1[1], h1, acc1, 0, 0, 0);

            // pack-convert FIRST (rtz), relu AFTER as packed f16 max (commutes with rtz)
            f16x8 h2f0 = __builtin_elementwise_max(
                words_to_frag(pkrtz(acc1[0],  acc1[1]),  pkrtz(acc1[2],  acc1[3]),
                              pkrtz(acc1[4],  acc1[5]),  pkrtz(acc1[6],  acc1[7])), z8);
            f16x8 h2f1 = __builtin_elementwise_max(
                words_to_frag(pkrtz(acc1[8],  acc1[9]),  pkrtz(acc1[10], acc1[11]),
                              pkrtz(acc1[12], acc1[13]), pkrtz(acc1[14], acc1[15])), z8);

            // layer 2
            f32x16 acc2 = __builtin_amdgcn_mfma_f32_32x32x16_f16(a2[0], h2f0, bias2, 0, 0, 0);
            acc2        = __builtin_amdgcn_mfma_f32_32x32x16_f16(a2[1], h2f1, acc2, 0, 0, 0);

            // shared accumulation of relu(h3) across all 4 p-chains
            sacc += __builtin_elementwise_max(acc2, (f32x16)0.0f);
        }
    }

    // ---- block reduce: lanes within 32-half, then waves via LDS ----
    float red[16];
    #pragma unroll
    for (int r = 0; r < 16; ++r) {
        float v = sacc[r];
        #pragma unroll
        for (int m = 1; m < 32; m <<= 1) v += __shfl_xor(v, m, 32);
        red[r] = v;
    }
    __shared__ float smem[4][32];
    if (col == 0) {
        #pragma unroll
        for (int r = 0; r < 16; ++r)
            smem[w][(r & 3) + 8 * (r >> 2) + 4 * hi] = red[r];
    }
    __syncthreads();
    if (tid < 32) {
        float s = smem[0][tid] + smem[1][tid] + smem[2][tid] + smem[3][tid];
        // scaled fixed-point: order-independent integer accumulation (deterministic)
        unsigned long long iv = (unsigned long long)(long long)rintf(s * SCALE);
        atomicAdd(&acc[batch * 32 + tid], iv);
    }
    __syncthreads();   // drains the atomics (compiler emits vmcnt(0) before barrier)

    __shared__ int lastFlag;
    if (tid == 0) {
        __threadfence();
        unsigned int old = atomicAdd(counter, 1u);
        lastFlag = (old == (unsigned)(gridDim.x - 1));
    }
    __syncthreads();
    if (!lastFlag) return;

    // ---- last block: MLP head for all 32 batches ----
    __shared__ float sb[32][32];
    __shared__ float fb[32][32];
    #pragma unroll
    for (int idx = tid; idx < 1024; idx += 256) {
        unsigned long long v = atomicAdd(&acc[idx], 0ULL);   // device-scope coherent read
        sb[idx >> 5][idx & 31] = (float)(long long)v * INV_SCALE;
    }
    __syncthreads();
    #pragma unroll
    for (int idx = tid; idx < 1024; idx += 256) {
        int b = idx >> 5, n = idx & 31;
        float f = bp[n];
        #pragma unroll
        for (int k = 0; k < 32; ++k) f += sb[b][k] * Wp[k * 32 + n];
        fb[b][n] = fmaxf(f, 0.f);
    }
    __syncthreads();
    #pragma unroll
    for (int idx = tid; idx < 1024; idx += 256) {
        int b = idx >> 5, n = idx & 31;
        float o = bo[n];
        #pragma unroll
        for (int k = 0; k < 32; ++k) o += fb[b][k] * Wo[k * 32 + n];
        out[b * 32 + n] = o;
    }
}

extern "C" void kernel_launch(void* const* d_in, const int* in_sizes, int n_in,
                              void* d_out, int out_size, void* d_ws, size_t ws_size,
                              hipStream_t stream)
{
    const float* x  = (const float*)d_in[0];
    const float* W0 = (const float*)d_in[1];
    const float* b0 = (const float*)d_in[2];
    const float* W1 = (const float*)d_in[3];
    const float* b1 = (const float*)d_in[4];
    const float* W2 = (const float*)d_in[5];
    const float* b2 = (const float*)d_in[6];
    const float* Wp = (const float*)d_in[7];
    const float* bp = (const float*)d_in[8];
    const float* Wo = (const float*)d_in[9];
    const float* bo = (const float*)d_in[10];
    float* out = (float*)d_out;

    _Float16* Ap = (_Float16*)d_ws;                               // 262144 halves (512 KB)
    _Float16* Bp = Ap + 32 * LL * NF;                             // 262144 halves (512 KB)
    unsigned long long* acc = (unsigned long long*)(Bp + 32 * LL * NF);  // 1024 u64 + counter
    unsigned int* counter   = (unsigned int*)(acc + 1024);

    rn_pre <<<1024, 256, 0, stream>>>(x, W0, b0, Ap, Bp, acc);
    rn_main<<<2048, 256, 0, stream>>>(Ap, Bp, W1, b1, W2, b2,
                                      acc, counter, Wp, bp, Wo, bo, out);
}

// Round 8
// 31.141 us; speedup vs baseline: 1.8583x; 1.8583x over previous
//
#include <hip/hip_runtime.h>
#include <hip/hip_bf16.h>

typedef float    f32x4  __attribute__((ext_vector_type(4)));
typedef float    f32x16 __attribute__((ext_vector_type(16)));
typedef int      i32x4  __attribute__((ext_vector_type(4)));
typedef _Float16 f16x8  __attribute__((ext_vector_type(8)));

#define LL 256   // h*w
#define NF 32    // hidden dim
#define NCH 64   // channels

// HW pack: two f32 -> u32 of two fp16 (v_cvt_pkrtz_f16_f32)
__device__ __forceinline__ unsigned pkrtz(float lo, float hi) {
    return __builtin_bit_cast(unsigned, __builtin_amdgcn_cvt_pkrtz(lo, hi));
}

__device__ __forceinline__ f16x8 words_to_frag(unsigned w0, unsigned w1, unsigned w2, unsigned w3) {
    i32x4 w;
    w.x = (int)w0; w.y = (int)w1; w.z = (int)w2; w.w = (int)w3;
    return __builtin_bit_cast(f16x8, w);
}

// ---------------- phase 0: A' = o@W0[:64]+b0 (fp16); B = o@W0[64:] (fp16); + lane tables ----------
// Block 0 threads 0..63 additionally build the per-lane MFMA fragment tables (a1/a2, with the
// phi hidden-dim permutation folded into a2) and the bias tables in C/D register layout.
__global__ __launch_bounds__(256) void rn_pre(
    const float* __restrict__ x, const float* __restrict__ W0,
    const float* __restrict__ b0, const float* __restrict__ W1, const float* __restrict__ b1,
    const float* __restrict__ W2, const float* __restrict__ b2,
    _Float16* __restrict__ Ap, _Float16* __restrict__ Bp,
    _Float16* __restrict__ fragTab, float* __restrict__ biasTab)
{
    int tid = threadIdx.x;
    if (blockIdx.x == 0 && tid < 64) {
        const int hi2 = tid >> 5, colv = tid & 31;
        #pragma unroll
        for (int kh = 0; kh < 2; ++kh) {
            f16x8 f1, f2;
            #pragma unroll
            for (int e = 0; e < 8; ++e) {
                int k  = kh * 16 + 8 * hi2 + e;
                int bk = (k >> 2) & 3;
                int fk = (bk == 1 || bk == 2) ? (k ^ 12) : k;   // phi
                f1[e] = (_Float16)W1[k  * NF + colv];
                f2[e] = (_Float16)W2[fk * NF + colv];
            }
            *(f16x8*)(fragTab + ((0 + kh) * 64 + tid) * 8) = f1;
            *(f16x8*)(fragTab + ((2 + kh) * 64 + tid) * 8) = f2;
        }
        // biasTab[table*32 + hi*16 + r] = b{1,2}[(r&3)+8*(r>>2)+4*hi]
        {
            int table = tid >> 5;           // 0 or 1
            int hh    = (tid >> 4) & 1;
            int r     = tid & 15;
            int row   = (r & 3) + 8 * (r >> 2) + 4 * hh;
            biasTab[table * 32 + hh * 16 + r] = table ? b2[row] : b1[row];
            if (tid < 32) {                 // second hi half for each table
                int t2 = tid >> 4, h2 = 1, r2 = tid & 15;
                (void)t2; (void)h2; (void)r2;
            }
        }
    }
    // full biasTab coverage needs 64 entries; tid<64 covers exactly 64 -> done above.

    int gid = blockIdx.x * 256 + tid;   // 32*256*32 = 262144 threads
    int k  = gid & 31;
    int bl = gid >> 5;          // b*256 + l
    int b  = bl >> 8;
    int l  = bl & 255;
    const float* xrow = x + b * NCH * LL + l;   // x[b][ch][l]
    float accA = 0.f, accB = 0.f;
    #pragma unroll 8
    for (int ch = 0; ch < NCH; ++ch) {
        float xv = xrow[ch * LL];
        accA += xv * W0[ch * NF + k];
        accB += xv * W0[(NCH + ch) * NF + k];
    }
    Ap[gid] = (_Float16)(accA + b0[k]);
    Bp[gid] = (_Float16)accB;
}

// ---------------- phase 1: fused pair loop, 4-way ILP, table-driven setup ----------------
// grid: 2048 blocks (XCD-swizzled) = 32 batches x 16 pgroups x 4 qchunks; 256 threads (4 waves).
// Wave owns 4 consecutive p's x 2 q-tiles; the 4 p-chains share the A'-tile load and one sacc.
__global__ __launch_bounds__(256) void rn_main(
    const _Float16* __restrict__ Ap, const _Float16* __restrict__ Bp,
    const _Float16* __restrict__ fragTab, const float* __restrict__ biasTab,
    float* __restrict__ partials)
{
    const int tid  = threadIdx.x;
    const int lane = tid & 63;
    const int w    = tid >> 6;
    const int col  = lane & 31;
    const int hi   = lane >> 5;
    // bijective XCD-contiguous swizzle (2048 % 8 == 0)
    const int bid  = (blockIdx.x & 7) * 256 + (blockIdx.x >> 3);
    const int batch  = bid >> 6;
    const int rem    = bid & 63;
    const int pgroup = rem >> 2;    // 0..15
    const int qchunk = rem & 3;     // 0..3
    const int pbase  = pgroup * 16 + w * 4;
    const int q0base = qchunk * 64;

    // ---- setup from precomputed tables: 12 coalesced 16B loads ----
    f16x8 a1[2], a2[2];
    a1[0] = *(const f16x8*)(fragTab + (0 * 64 + lane) * 8);
    a1[1] = *(const f16x8*)(fragTab + (1 * 64 + lane) * 8);
    a2[0] = *(const f16x8*)(fragTab + (2 * 64 + lane) * 8);
    a2[1] = *(const f16x8*)(fragTab + (3 * 64 + lane) * 8);

    f32x16 bias1, bias2, sacc;
    {
        const f32x4* bt1 = (const f32x4*)(biasTab + hi * 16);
        const f32x4* bt2 = (const f32x4*)(biasTab + 32 + hi * 16);
        #pragma unroll
        for (int j = 0; j < 4; ++j) {
            f32x4 v1 = bt1[j], v2 = bt2[j];
            #pragma unroll
            for (int e = 0; e < 4; ++e) {
                bias1[j * 4 + e] = v1[e];
                bias2[j * 4 + e] = v2[e];
                sacc[j * 4 + e]  = 0.f;
            }
        }
    }

    // ---- B rows for the wave's 4 p's (fragment order) ----
    f16x8 bq0[4], bq1[4];
    #pragma unroll
    for (int i = 0; i < 4; ++i) {
        const _Float16* Brow = Bp + (batch * LL + pbase + i) * NF + 8 * hi;
        bq0[i] = *(const f16x8*)(Brow);
        bq1[i] = *(const f16x8*)(Brow + 16);
    }

    const _Float16* Abase = Ap + batch * LL * NF + 8 * hi;
    const f16x8 z8 = {};

    #pragma unroll
    for (int t = 0; t < 2; ++t) {
        const _Float16* Arow = Abase + (q0base + t * 32 + col) * NF;
        f16x8 t0 = *(const f16x8*)(Arow);
        f16x8 t1 = *(const f16x8*)(Arow + 16);

        #pragma unroll
        for (int i = 0; i < 4; ++i) {
            // h1 = relu(A'[q] + B[p_i]) in fp16 -> MFMA B-operand fragments directly
            f16x8 h0 = __builtin_elementwise_max(t0 + bq0[i], z8);
            f16x8 h1 = __builtin_elementwise_max(t1 + bq1[i], z8);

            // layer 1 (bias as C-input)
            f32x16 acc1 = __builtin_amdgcn_mfma_f32_32x32x16_f16(a1[0], h0, bias1, 0, 0, 0);
            acc1        = __builtin_amdgcn_mfma_f32_32x32x16_f16(a1[1], h1, acc1, 0, 0, 0);

            // pack-convert (rtz) then relu as packed f16 max (commutes with rtz)
            f16x8 h2f0 = __builtin_elementwise_max(
                words_to_frag(pkrtz(acc1[0],  acc1[1]),  pkrtz(acc1[2],  acc1[3]),
                              pkrtz(acc1[4],  acc1[5]),  pkrtz(acc1[6],  acc1[7])), z8);
            f16x8 h2f1 = __builtin_elementwise_max(
                words_to_frag(pkrtz(acc1[8],  acc1[9]),  pkrtz(acc1[10], acc1[11]),
                              pkrtz(acc1[12], acc1[13]), pkrtz(acc1[14], acc1[15])), z8);

            // layer 2
            f32x16 acc2 = __builtin_amdgcn_mfma_f32_32x32x16_f16(a2[0], h2f0, bias2, 0, 0, 0);
            acc2        = __builtin_amdgcn_mfma_f32_32x32x16_f16(a2[1], h2f1, acc2, 0, 0, 0);

            // shared accumulation of relu(h3) across all 4 p-chains
            sacc += __builtin_elementwise_max(acc2, (f32x16)0.0f);
        }
    }

    // ---- block reduce: lanes within 32-half, then waves via LDS ----
    float red[16];
    #pragma unroll
    for (int r = 0; r < 16; ++r) {
        float v = sacc[r];
        #pragma unroll
        for (int m = 1; m < 32; m <<= 1) v += __shfl_xor(v, m, 32);
        red[r] = v;
    }
    __shared__ float smem[4][32];
    if (col == 0) {
        #pragma unroll
        for (int r = 0; r < 16; ++r)
            smem[w][(r & 3) + 8 * (r >> 2) + 4 * hi] = red[r];
    }
    __syncthreads();
    if (tid < 32) {
        float s = smem[0][tid] + smem[1][tid] + smem[2][tid] + smem[3][tid];
        partials[bid * 32 + tid] = s;   // bid = batch*64 + rem : contiguous per batch
    }
}

// ---------------- phase 2: per-batch reduce + MLP head (32 blocks) ----------------
__global__ __launch_bounds__(256) void rn_post(
    const float* __restrict__ partials,
    const float* __restrict__ Wp, const float* __restrict__ bp,
    const float* __restrict__ Wo, const float* __restrict__ bo,
    float* __restrict__ out)
{
    const int b   = blockIdx.x;       // 32 blocks, one per batch
    const int tid = threadIdx.x;      // 256 threads
    const int grp = tid >> 5, n = tid & 31;
    __shared__ float red[8][32];
    float s = 0.f;
    #pragma unroll
    for (int j = 0; j < 8; ++j)
        s += partials[(b * 64 + grp * 8 + j) * 32 + n];
    red[grp][n] = s;
    __syncthreads();
    if (tid < 32) {
        float sv = 0.f;
        #pragma unroll
        for (int g = 0; g < 8; ++g) sv += red[g][tid];
        float f = bp[tid];
        #pragma unroll
        for (int k = 0; k < 32; ++k)
            f += __shfl(sv, k, 32) * Wp[k * 32 + tid];
        f = fmaxf(f, 0.f);
        float o = bo[tid];
        #pragma unroll
        for (int k = 0; k < 32; ++k)
            o += __shfl(f, k, 32) * Wo[k * 32 + tid];
        out[b * 32 + tid] = o;
    }
}

extern "C" void kernel_launch(void* const* d_in, const int* in_sizes, int n_in,
                              void* d_out, int out_size, void* d_ws, size_t ws_size,
                              hipStream_t stream)
{
    const float* x  = (const float*)d_in[0];
    const float* W0 = (const float*)d_in[1];
    const float* b0 = (const float*)d_in[2];
    const float* W1 = (const float*)d_in[3];
    const float* b1 = (const float*)d_in[4];
    const float* W2 = (const float*)d_in[5];
    const float* b2 = (const float*)d_in[6];
    const float* Wp = (const float*)d_in[7];
    const float* bp = (const float*)d_in[8];
    const float* Wo = (const float*)d_in[9];
    const float* bo = (const float*)d_in[10];
    float* out = (float*)d_out;

    _Float16* Ap       = (_Float16*)d_ws;                 // 262144 halves (512 KB)
    _Float16* Bp       = Ap + 32 * LL * NF;               // 262144 halves (512 KB)
    float*    partials = (float*)(Bp + 32 * LL * NF);     // 2048*32 f32 (256 KB)
    _Float16* fragTab  = (_Float16*)(partials + 2048 * 32);  // 4*64*8 halves (4 KB)
    float*    biasTab  = (float*)(fragTab + 4 * 64 * 8);     // 64 f32 (256 B)

    rn_pre <<<1024, 256, 0, stream>>>(x, W0, b0, W1, b1, W2, b2, Ap, Bp, fragTab, biasTab);
    rn_main<<<2048, 256, 0, stream>>>(Ap, Bp, fragTab, biasTab, partials);
    rn_post<<<32, 256, 0, stream>>>(partials, Wp, bp, Wo, bo, out);
}

// Round 9
// 29.998 us; speedup vs baseline: 1.9291x; 1.0381x over previous
//
#include <hip/hip_runtime.h>
#include <hip/hip_bf16.h>

typedef float    f32x4  __attribute__((ext_vector_type(4)));
typedef float    f32x16 __attribute__((ext_vector_type(16)));
typedef int      i32x4  __attribute__((ext_vector_type(4)));
typedef _Float16 f16x8  __attribute__((ext_vector_type(8)));

#define LL 256   // h*w
#define NF 32    // hidden dim
#define NCH 64   // channels

// HW pack: two f32 -> u32 of two fp16 (v_cvt_pkrtz_f16_f32)
__device__ __forceinline__ unsigned pkrtz(float lo, float hi) {
    return __builtin_bit_cast(unsigned, __builtin_amdgcn_cvt_pkrtz(lo, hi));
}

__device__ __forceinline__ f16x8 words_to_frag(unsigned w0, unsigned w1, unsigned w2, unsigned w3) {
    i32x4 w;
    w.x = (int)w0; w.y = (int)w1; w.z = (int)w2; w.w = (int)w3;
    return __builtin_bit_cast(f16x8, w);
}

// ---------------- phase 0: A' = o@W0[:64]+b0 (fp16); B = o@W0[64:] (fp16); + lane tables ----------
__global__ __launch_bounds__(256) void rn_pre(
    const float* __restrict__ x, const float* __restrict__ W0,
    const float* __restrict__ b0, const float* __restrict__ W1, const float* __restrict__ b1,
    const float* __restrict__ W2, const float* __restrict__ b2,
    _Float16* __restrict__ Ap, _Float16* __restrict__ Bp,
    _Float16* __restrict__ fragTab, float* __restrict__ biasTab)
{
    int tid = threadIdx.x;
    if (blockIdx.x == 0 && tid < 64) {
        const int hi2 = tid >> 5, colv = tid & 31;
        #pragma unroll
        for (int kh = 0; kh < 2; ++kh) {
            f16x8 f1, f2;
            #pragma unroll
            for (int e = 0; e < 8; ++e) {
                int k  = kh * 16 + 8 * hi2 + e;
                int bk = (k >> 2) & 3;
                int fk = (bk == 1 || bk == 2) ? (k ^ 12) : k;   // phi
                f1[e] = (_Float16)W1[k  * NF + colv];
                f2[e] = (_Float16)W2[fk * NF + colv];
            }
            *(f16x8*)(fragTab + ((0 + kh) * 64 + tid) * 8) = f1;
            *(f16x8*)(fragTab + ((2 + kh) * 64 + tid) * 8) = f2;
        }
        // biasTab[table*32 + hh*16 + r] = b{1,2}[(r&3)+8*(r>>2)+4*hh]
        int table = tid >> 5;
        int hh    = (tid >> 4) & 1;
        int r     = tid & 15;
        int row   = (r & 3) + 8 * (r >> 2) + 4 * hh;
        biasTab[table * 32 + hh * 16 + r] = table ? b2[row] : b1[row];
    }

    int gid = blockIdx.x * 256 + tid;   // 32*256*32 = 262144 threads
    int k  = gid & 31;
    int bl = gid >> 5;          // b*256 + l
    int b  = bl >> 8;
    int l  = bl & 255;
    const float* xrow = x + b * NCH * LL + l;   // x[b][ch][l]
    float accA = 0.f, accB = 0.f;
    #pragma unroll 8
    for (int ch = 0; ch < NCH; ++ch) {
        float xv = xrow[ch * LL];
        accA += xv * W0[ch * NF + k];
        accB += xv * W0[(NCH + ch) * NF + k];
    }
    Ap[gid] = (_Float16)(accA + b0[k]);
    Bp[gid] = (_Float16)accB;
}

// ---------------- phase 1: fused pair loop, 4-way ILP, table setup, LDS tail reduce ----------------
// grid: 2048 blocks (XCD-swizzled) = 32 batches x 16 pgroups x 4 qchunks; 256 threads (4 waves).
// Wave owns 4 consecutive p's x 2 q-tiles; 4 p-chains share the A'-tile loads and one sacc.
__global__ __launch_bounds__(256) void rn_main(
    const _Float16* __restrict__ Ap, const _Float16* __restrict__ Bp,
    const _Float16* __restrict__ fragTab, const float* __restrict__ biasTab,
    float* __restrict__ partials)
{
    const int tid  = threadIdx.x;
    const int lane = tid & 63;
    const int w    = tid >> 6;
    const int col  = lane & 31;
    const int hi   = lane >> 5;
    // bijective XCD-contiguous swizzle (2048 % 8 == 0)
    const int bid  = (blockIdx.x & 7) * 256 + (blockIdx.x >> 3);
    const int batch  = bid >> 6;
    const int rem    = bid & 63;
    const int pgroup = rem >> 2;    // 0..15
    const int qchunk = rem & 3;     // 0..3
    const int pbase  = pgroup * 16 + w * 4;
    const int q0base = qchunk * 64;

    // ---- setup from precomputed tables: coalesced vector loads ----
    f16x8 a1[2], a2[2];
    a1[0] = *(const f16x8*)(fragTab + (0 * 64 + lane) * 8);
    a1[1] = *(const f16x8*)(fragTab + (1 * 64 + lane) * 8);
    a2[0] = *(const f16x8*)(fragTab + (2 * 64 + lane) * 8);
    a2[1] = *(const f16x8*)(fragTab + (3 * 64 + lane) * 8);

    f32x16 bias1, bias2, sacc;
    {
        const f32x4* bt1 = (const f32x4*)(biasTab + hi * 16);
        const f32x4* bt2 = (const f32x4*)(biasTab + 32 + hi * 16);
        #pragma unroll
        for (int j = 0; j < 4; ++j) {
            f32x4 v1 = bt1[j], v2 = bt2[j];
            #pragma unroll
            for (int e = 0; e < 4; ++e) {
                bias1[j * 4 + e] = v1[e];
                bias2[j * 4 + e] = v2[e];
                sacc[j * 4 + e]  = 0.f;
            }
        }
    }

    // ---- B rows for the wave's 4 p's (fragment order) ----
    f16x8 bq0[4], bq1[4];
    #pragma unroll
    for (int i = 0; i < 4; ++i) {
        const _Float16* Brow = Bp + (batch * LL + pbase + i) * NF + 8 * hi;
        bq0[i] = *(const f16x8*)(Brow);
        bq1[i] = *(const f16x8*)(Brow + 16);
    }

    // ---- hoisted A'-tile loads: both q-tiles issue before any compute ----
    const _Float16* Abase = Ap + batch * LL * NF + 8 * hi;
    const _Float16* Arow0 = Abase + (q0base + col) * NF;
    const _Float16* Arow1 = Abase + (q0base + 32 + col) * NF;
    f16x8 ta[4];
    ta[0] = *(const f16x8*)(Arow0);
    ta[1] = *(const f16x8*)(Arow0 + 16);
    ta[2] = *(const f16x8*)(Arow1);
    ta[3] = *(const f16x8*)(Arow1 + 16);

    const f16x8 z8 = {};

    #pragma unroll
    for (int t = 0; t < 2; ++t) {
        #pragma unroll
        for (int i = 0; i < 4; ++i) {
            // h1 = relu(A'[q] + B[p_i]) in fp16 -> MFMA B-operand fragments directly
            f16x8 h0 = __builtin_elementwise_max(ta[t * 2]     + bq0[i], z8);
            f16x8 h1 = __builtin_elementwise_max(ta[t * 2 + 1] + bq1[i], z8);

            // layer 1 (bias as C-input)
            f32x16 acc1 = __builtin_amdgcn_mfma_f32_32x32x16_f16(a1[0], h0, bias1, 0, 0, 0);
            acc1        = __builtin_amdgcn_mfma_f32_32x32x16_f16(a1[1], h1, acc1, 0, 0, 0);

            // pack-convert (rtz) then relu as packed f16 max (commutes with rtz)
            f16x8 h2f0 = __builtin_elementwise_max(
                words_to_frag(pkrtz(acc1[0],  acc1[1]),  pkrtz(acc1[2],  acc1[3]),
                              pkrtz(acc1[4],  acc1[5]),  pkrtz(acc1[6],  acc1[7])), z8);
            f16x8 h2f1 = __builtin_elementwise_max(
                words_to_frag(pkrtz(acc1[8],  acc1[9]),  pkrtz(acc1[10], acc1[11]),
                              pkrtz(acc1[12], acc1[13]), pkrtz(acc1[14], acc1[15])), z8);

            // layer 2
            f32x16 acc2 = __builtin_amdgcn_mfma_f32_32x32x16_f16(a2[0], h2f0, bias2, 0, 0, 0);
            acc2        = __builtin_amdgcn_mfma_f32_32x32x16_f16(a2[1], h2f1, acc2, 0, 0, 0);

            // shared accumulation of relu(h3) across all 4 p-chains
            sacc += __builtin_elementwise_max(acc2, (f32x16)0.0f);
        }
    }

    // ---- 3-stage LDS tail reduce (replaces 80-op shfl butterfly) ----
    // P[tid*20 + r] = sacc[r]  (stride 20 dwords: 16B-aligned, bank-spread)
    __shared__ float P[256 * 20];
    __shared__ float Q[8][32];
    #pragma unroll
    for (int j = 0; j < 4; ++j) {
        f32x4 v;
        v.x = sacc[j * 4 + 0]; v.y = sacc[j * 4 + 1];
        v.z = sacc[j * 4 + 2]; v.w = sacc[j * 4 + 3];
        *(f32x4*)&P[tid * 20 + j * 4] = v;
    }
    __syncthreads();
    {
        // thread t: output row = t&31, part = t>>5 encodes (wave, col-half)
        const int row  = tid & 31;
        const int part = tid >> 5;
        const int wq   = part >> 1;
        const int colh = (part & 1) << 4;
        const int hir  = (row >> 2) & 1;
        const int rr   = (row & 3) | ((row >> 3) << 2);
        const int base = (wq * 64 + hir * 32 + colh) * 20 + rr;
        float s = 0.f;
        #pragma unroll
        for (int j = 0; j < 16; ++j) s += P[base + j * 20];
        Q[part][row] = s;
    }
    __syncthreads();
    if (tid < 32) {
        float s = 0.f;
        #pragma unroll
        for (int g = 0; g < 8; ++g) s += Q[g][tid];
        partials[bid * 32 + tid] = s;   // bid = batch*64 + rem : contiguous per batch
    }
}

// ---------------- phase 2: per-batch reduce + MLP head (32 blocks) ----------------
__global__ __launch_bounds__(256) void rn_post(
    const float* __restrict__ partials,
    const float* __restrict__ Wp, const float* __restrict__ bp,
    const float* __restrict__ Wo, const float* __restrict__ bo,
    float* __restrict__ out)
{
    const int b   = blockIdx.x;       // 32 blocks, one per batch
    const int tid = threadIdx.x;      // 256 threads
    const int grp = tid >> 5, n = tid & 31;
    __shared__ float red[8][32];
    float s = 0.f;
    #pragma unroll
    for (int j = 0; j < 8; ++j)
        s += partials[(b * 64 + grp * 8 + j) * 32 + n];
    red[grp][n] = s;
    __syncthreads();
    if (tid < 32) {
        float sv = 0.f;
        #pragma unroll
        for (int g = 0; g < 8; ++g) sv += red[g][tid];
        float f = bp[tid];
        #pragma unroll
        for (int k = 0; k < 32; ++k)
            f += __shfl(sv, k, 32) * Wp[k * 32 + tid];
        f = fmaxf(f, 0.f);
        float o = bo[tid];
        #pragma unroll
        for (int k = 0; k < 32; ++k)
            o += __shfl(f, k, 32) * Wo[k * 32 + tid];
        out[b * 32 + tid] = o;
    }
}

extern "C" void kernel_launch(void* const* d_in, const int* in_sizes, int n_in,
                              void* d_out, int out_size, void* d_ws, size_t ws_size,
                              hipStream_t stream)
{
    const float* x  = (const float*)d_in[0];
    const float* W0 = (const float*)d_in[1];
    const float* b0 = (const float*)d_in[2];
    const float* W1 = (const float*)d_in[3];
    const float* b1 = (const float*)d_in[4];
    const float* W2 = (const float*)d_in[5];
    const float* b2 = (const float*)d_in[6];
    const float* Wp = (const float*)d_in[7];
    const float* bp = (const float*)d_in[8];
    const float* Wo = (const float*)d_in[9];
    const float* bo = (const float*)d_in[10];
    float* out = (float*)d_out;

    _Float16* Ap       = (_Float16*)d_ws;                 // 262144 halves (512 KB)
    _Float16* Bp       = Ap + 32 * LL * NF;               // 262144 halves (512 KB)
    float*    partials = (float*)(Bp + 32 * LL * NF);     // 2048*32 f32 (256 KB)
    _Float16* fragTab  = (_Float16*)(partials + 2048 * 32);  // 4*64*8 halves (4 KB)
    float*    biasTab  = (float*)(fragTab + 4 * 64 * 8);     // 64 f32 (256 B)

    rn_pre <<<1024, 256, 0, stream>>>(x, W0, b0, W1, b1, W2, b2, Ap, Bp, fragTab, biasTab);
    rn_main<<<2048, 256, 0, stream>>>(Ap, Bp, fragTab, biasTab, partials);
    rn_post<<<32, 256, 0, stream>>>(partials, Wp, bp, Wo, bo, out);
}